// Round 8
// baseline (205.912 us; speedup 1.0000x reference)
//
#include <hip/hip_runtime.h>

// Problem constants (match reference)
#define BB 8
#define CC 3
#define HH 1024
#define WW 1024
#define NS 15728        // int(1024*1024*0.015)
#define NG (NS / 4)     // 3932 int4 groups (NS % 4 == 0)

// Gaussian 5-tap, sigma=1.5, normalized
#define G0 0.1200784f
#define G1 0.2338808f
#define G2 0.2920816f

// ---------------------------------------------------------------------------
// Kernel 1: snow boxes -> per-batch bitmask [B][H][W/32], built per 32-col
// stripe in LDS (1 word/row, 4 KiB). 256 blocks (32 stripes x 8 batches).
// Spots scanned as int4 with one-group-ahead prefetch. No memset needed.
// (verified fast in rounds 3-6; unchanged)
// ---------------------------------------------------------------------------
#define NSTRIPE 32

__global__ __launch_bounds__(256) void snow_mask_kernel(
    const int* __restrict__ ys, const int* __restrict__ xs,
    const int* __restrict__ rs, unsigned int* __restrict__ mbits) {
  __shared__ unsigned int lm[HH];
  const int b = blockIdx.y;
  const int sx0 = blockIdx.x << 5;  // 32-col stripe
  const int tid = threadIdx.x;

  for (int i = tid; i < HH; i += 256) lm[i] = 0u;
  __syncthreads();

  const int4* __restrict__ y4 = (const int4*)(ys + b * NS);
  const int4* __restrict__ x4 = (const int4*)(xs + b * NS);
  const int4* __restrict__ r4 = (const int4*)(rs + b * NS);

  auto spot = [&](int y, int x, int r) {
    r += 1;  // radius in {1,2,3}
    int x0 = max(x - r, sx0), x1 = min(x + r, sx0 + 31);
    if (x0 > x1) return;  // box misses this stripe (~97% reject)
    int y0 = max(y - r, 0), y1 = min(y + r, HH - 1);
    unsigned m = (0xFFFFFFFFu << (x0 & 31)) & (0xFFFFFFFFu >> (31 - (x1 & 31)));
    for (int py = y0; py <= y1; ++py) atomicOr(&lm[py], m);
  };

  int g = tid;
  int4 Y = {0, 0, 0, 0}, X = {0, 0, 0, 0}, R = {0, 0, 0, 0};
  bool have = g < NG;
  if (have) { Y = y4[g]; X = x4[g]; R = r4[g]; }
  while (have) {
    int gn = g + 256;
    int4 Yn = {0, 0, 0, 0}, Xn = {0, 0, 0, 0}, Rn = {0, 0, 0, 0};
    bool haven = gn < NG;
    if (haven) { Yn = y4[gn]; Xn = x4[gn]; Rn = r4[gn]; }  // prefetch
    spot(Y.x, X.x, R.x);
    spot(Y.y, X.y, R.y);
    spot(Y.z, X.z, R.z);
    spot(Y.w, X.w, R.w);
    g = gn; Y = Yn; X = Xn; R = Rn; have = haven;
  }
  __syncthreads();

  unsigned int* dst = mbits + ((unsigned)(b * HH) << 5) + blockIdx.x;
  for (int i = tid; i < HH; i += 256) dst[i << 5] = lm[i];
}

// ---------------------------------------------------------------------------
// Kernel 2: masked-fill (0.95) + separable 5x5 Gaussian + clip, fused.
// Root cause from rounds 5/6: the written 7-row pipeline needs ~70 live asm
// load-dest VGPRs but compiled to VGPR=48 -> the compiler collapsed the
// pipeline (identical perf across 3 "pipelined" variants). Fix: cut per-row
// cost 10->8 regs and loads 5->4 by replacing the L/R halo LOADS with
// __shfl of the post-fill values (neighbor lane already holds them).
// Only wave-edge lanes (0/63) carry real halo data via per-lane-addressed
// float2 + extra mask word (middle lanes load L1-hit duplicates).
// Launch geometry = round-6 verified shape (traffic: FETCH 62MB/WRITE 96MB).
// ---------------------------------------------------------------------------
#define RROWS 16

template <int N>
__device__ __forceinline__ void wait_vmcnt() {
  asm volatile("s_waitcnt vmcnt(%0)" ::"n"(N) : "memory");
  __builtin_amdgcn_sched_barrier(0);
}

__device__ __forceinline__ void ld4(const float* p, float4& d) {
  asm volatile("global_load_dwordx4 %0, %1, off" : "=v"(d) : "v"(p));
}
__device__ __forceinline__ void ld2(const float* p, float2& d) {
  asm volatile("global_load_dwordx2 %0, %1, off" : "=v"(d) : "v"(p));
}
__device__ __forceinline__ void ld1(const unsigned* p, unsigned& d) {
  asm volatile("global_load_dword %0, %1, off" : "=v"(d) : "v"(p));
}

struct Row {
  float4 B;      // cols col..col+3
  float2 E;      // edge-lane halo (lane0: col-2,col-1; lane63: col+4,col+5)
  unsigned m0;   // mask word holding col..col+3
  unsigned m1;   // mask word holding E's bits
};

__global__ __launch_bounds__(256, 4) void snow_blur_kernel(
    const float* __restrict__ x, const unsigned int* __restrict__ mbits,
    float* __restrict__ out) {
  const int bz = blockIdx.y;        // b*CC + c
  const int b = bz / CC;
  const int gy0 = blockIdx.x * RROWS;
  const int tid = threadIdx.x;
  const int col = tid << 2;         // block spans full 1024-col width
  const int lane = tid & 63;        // wave covers 256 contiguous cols

  const float* __restrict__ xp = x + (size_t)bz * (HH * WW);
  const unsigned int* __restrict__ mb = mbits + ((unsigned)(b * HH) << 5);

  // loop-invariant per-lane geometry
  const int s5 = col & 31;                        // bit pos of col in m0
  const int w0 = col >> 5;                        // mask word of own cols
  const bool l0 = (lane == 0), l63 = (lane == 63);
  // edge-halo column (middle lanes: own col -> L1-hit duplicate)
  const int eCol = l0 ? max(col - 2, 0) : (l63 ? min(col + 4, WW - 2) : col);
  const int ew = eCol >> 5;
  const int eshift = eCol & 31;
  // OOB sentinels: image edge -> halo is conv zero-padding
  const unsigned eoob = (l0 && col == 0) ? 16u
                        : ((l63 && col == WW - 4) ? 16u : 0u);

  // issue one row's 4 loads (asm: issue order fixed, cannot be sunk)
  auto issue = [&](int gy, Row& rw) {
    int gyc = min(max(gy, 0), HH - 1);
    const float* rp = xp + ((size_t)gyc << 10);
    const unsigned* mrow = mb + (gyc << 5);
    ld4(rp + col, rw.B);
    ld2(rp + eCol, rw.E);
    ld1(mrow + w0, rw.m0);
    ld1(mrow + ew, rw.m1);
  };

  // consume one staged row -> horizontal 5-tap for 4 cols
  auto consume = [&](const Row& rw, unsigned ro) {
    unsigned bB = ((rw.m0 >> s5) & 0xFu) | ro;
    float4 fB;
    fB.x = (bB & 1u) ? 0.95f : rw.B.x;
    fB.y = (bB & 2u) ? 0.95f : rw.B.y;
    fB.z = (bB & 4u) ? 0.95f : rw.B.z;
    fB.w = (bB & 8u) ? 0.95f : rw.B.w;
    if (bB & 16u) { fB.x = 0.f; fB.y = 0.f; fB.z = 0.f; fB.w = 0.f; }
    // edge-lane fixed halo
    unsigned bE = ((rw.m1 >> eshift) & 3u) | ro | eoob;
    float2 fE;
    fE.x = (bE & 1u) ? 0.95f : rw.E.x;
    fE.y = (bE & 2u) ? 0.95f : rw.E.y;
    if (bE & 16u) { fE.x = 0.f; fE.y = 0.f; }
    // halos from neighbor lanes' POST-FILL values (no loads)
    float lz = __shfl_up(fB.z, 1, 64);    // col-2
    float lw = __shfl_up(fB.w, 1, 64);    // col-1
    float rx = __shfl_down(fB.x, 1, 64);  // col+4
    float ry = __shfl_down(fB.y, 1, 64);  // col+5
    float2 fL, fR;
    fL.x = l0 ? fE.x : lz;
    fL.y = l0 ? fE.y : lw;
    fR.x = l63 ? fE.x : rx;
    fR.y = l63 ? fE.y : ry;
    float4 h;
    h.x = G0 * (fL.x + fB.z) + G1 * (fL.y + fB.y) + G2 * fB.x;
    h.y = G0 * (fL.y + fB.w) + G1 * (fB.x + fB.z) + G2 * fB.y;
    h.z = G0 * (fB.x + fR.x) + G1 * (fB.y + fB.w) + G2 * fB.z;
    h.w = G0 * (fB.y + fR.y) + G1 * (fB.z + fR.x) + G2 * fB.w;
    return h;
  };

  auto rof = [&](int gy) { return (gy < 0 || gy >= HH) ? 16u : 0u; };

  // ---- prologue: issue all 7 rows (28 loads), then counted consumes ----
  Row ra, rb, rc, rd, s0, s1, s2;
  issue(gy0 - 2, ra);
  issue(gy0 - 1, rb);
  issue(gy0 + 0, rc);
  issue(gy0 + 1, rd);
  issue(gy0 + 2, s0);
  issue(gy0 + 3, s1);
  issue(gy0 + 4, s2);
  wait_vmcnt<24>();
  float4 h0 = consume(ra, rof(gy0 - 2));
  wait_vmcnt<20>();
  float4 h1 = consume(rb, rof(gy0 - 1));
  wait_vmcnt<16>();
  float4 h2 = consume(rc, 0u);   // gy0..gy0+1 always in range
  wait_vmcnt<12>();
  float4 h3 = consume(rd, 0u);

  float* op = out + (size_t)bz * (HH * WW) + ((size_t)gy0 << 10) + col;

  // wait counts (4 loads/row, 1 store/iter, in-order vmcnt retirement):
  // k=0:12 k=1:13 k=2:14 k=3..12:15 k=13:11 k=14:7 k=15:3
#define STEP(K, WN)                                                     \
  {                                                                     \
    Row nr{};                                                           \
    if ((K) < RROWS - 3) issue(gy0 + 5 + (K), nr);                      \
    wait_vmcnt<WN>();                                                   \
    float4 h4 = consume(s0, rof(gy0 + 2 + (K)));                        \
    float4 sv;                                                          \
    sv.x = G0 * (h0.x + h4.x) + G1 * (h1.x + h3.x) + G2 * h2.x;         \
    sv.y = G0 * (h0.y + h4.y) + G1 * (h1.y + h3.y) + G2 * h2.y;         \
    sv.z = G0 * (h0.z + h4.z) + G1 * (h1.z + h3.z) + G2 * h2.z;         \
    sv.w = G0 * (h0.w + h4.w) + G1 * (h1.w + h3.w) + G2 * h2.w;         \
    sv.x = fminf(fmaxf(sv.x, 0.f), 1.f);                                \
    sv.y = fminf(fmaxf(sv.y, 0.f), 1.f);                                \
    sv.z = fminf(fmaxf(sv.z, 0.f), 1.f);                                \
    sv.w = fminf(fmaxf(sv.w, 0.f), 1.f);                                \
    *(float4*)op = sv;                                                  \
    op += WW;                                                           \
    s0 = s1; s1 = s2; s2 = nr;                                          \
    h0 = h1; h1 = h2; h2 = h3; h3 = h4;                                 \
  }

  STEP(0, 12)
  STEP(1, 13)
  STEP(2, 14)
  STEP(3, 15)
  STEP(4, 15)
  STEP(5, 15)
  STEP(6, 15)
  STEP(7, 15)
  STEP(8, 15)
  STEP(9, 15)
  STEP(10, 15)
  STEP(11, 15)
  STEP(12, 15)
  STEP(13, 11)
  STEP(14, 7)
  STEP(15, 3)
#undef STEP
}

// ---------------------------------------------------------------------------
extern "C" void kernel_launch(void* const* d_in, const int* in_sizes, int n_in,
                              void* d_out, int out_size, void* d_ws, size_t ws_size,
                              hipStream_t stream) {
  const float* x = (const float*)d_in[0];
  const int* ys = (const int*)d_in[1];
  const int* xs = (const int*)d_in[2];
  const int* rs = (const int*)d_in[3];
  float* out = (float*)d_out;

  unsigned int* mbits = (unsigned int*)d_ws;  // B*H*W/8 = 1 MiB
  // no memset: mask kernel fully overwrites every word of mbits

  dim3 mgrid(NSTRIPE, BB);
  snow_mask_kernel<<<mgrid, 256, 0, stream>>>(ys, xs, rs, mbits);

  dim3 grid(HH / RROWS, BB * CC);
  snow_blur_kernel<<<grid, 256, 0, stream>>>(x, mbits, out);
}